// Round 4
// baseline (154.295 us; speedup 1.0000x reference)
//
#include <hip/hip_runtime.h>

// Lorenz96 RK4, fp32 — persistent waves + ping-pong prefetch:
//   Grid = 2048 blocks x 256 (8 blocks/CU) = 524288 threads; each thread
//   grid-strides over exactly nf4/524288 (=10) float4 chunks. Two register
//   slots alternate: slot B's 4 stencil loads are issued BEFORE slot A's
//   compute, so HBM requests stay outstanding across the whole wave
//   lifetime instead of one burst per short-lived wave (the ~50us plateau
//   of rounds 0-3 was duty-cycle: one-shot waves idle the memory pipe
//   ~half their life; fill kernels stream 335MB in the same 50us).
//   Redundant-halo compute (window [p-8,p+7] = 4 aligned float4s of the
//   row, cols c-2,c-1,c,c+1 mod 10): zero cross-lane ops, no LDS.
//   Indexing is incremental: c_{next} = (c + stride) mod 10 via one
//   conditional subtract — no division in the loop.

#define FORCE 8.0f

__device__ __forceinline__ float4 rk4_chunk(const float4 vm2, const float4 vm1,
                                            const float4 v0,  const float4 vp1,
                                            const float dt,   const float hdt)
{
    float xa[16];
    xa[0]=vm2.x;  xa[1]=vm2.y;  xa[2]=vm2.z;  xa[3]=vm2.w;
    xa[4]=vm1.x;  xa[5]=vm1.y;  xa[6]=vm1.z;  xa[7]=vm1.w;
    xa[8]=v0.x;   xa[9]=v0.y;   xa[10]=v0.z;  xa[11]=v0.w;
    xa[12]=vp1.x; xa[13]=vp1.y; xa[14]=vp1.z; xa[15]=vp1.w;

    // d[i] = (x[i+1] - x[i-2]) * x[i-1] - x[i] + F; window-relative:
    //   D[i] = (S[i+3] - S[i]) * S[i+1] - S[i+2] + F  (window shrinks by 3)
    float k1[13], y1[13];
#pragma unroll
    for (int i = 0; i < 13; ++i)
        k1[i] = (xa[i+3] - xa[i]) * xa[i+1] - xa[i+2] + FORCE;
#pragma unroll
    for (int i = 0; i < 13; ++i)
        y1[i] = fmaf(hdt, k1[i], xa[i+2]);

    float k2[10], y2[10];
#pragma unroll
    for (int i = 0; i < 10; ++i)
        k2[i] = (y1[i+3] - y1[i]) * y1[i+1] - y1[i+2] + FORCE;
#pragma unroll
    for (int i = 0; i < 10; ++i)
        y2[i] = fmaf(hdt, k2[i], xa[i+4]);

    float k3[7], y3[7];
#pragma unroll
    for (int i = 0; i < 7; ++i)
        k3[i] = (y2[i+3] - y2[i]) * y2[i+1] - y2[i+2] + FORCE;
#pragma unroll
    for (int i = 0; i < 7; ++i)
        y3[i] = fmaf(dt, k3[i], xa[i+6]);

    float k4[4];
#pragma unroll
    for (int i = 0; i < 4; ++i)
        k4[i] = (y3[i+3] - y3[i]) * y3[i+1] - y3[i+2] + FORCE;

    const float sc = dt * (1.0f / 6.0f);
    float4 r;
    float t0 = k1[6] + k4[0]; t0 = fmaf(2.0f, k2[4], t0); t0 = fmaf(2.0f, k3[2], t0);
    float t1 = k1[7] + k4[1]; t1 = fmaf(2.0f, k2[5], t1); t1 = fmaf(2.0f, k3[3], t1);
    float t2 = k1[8] + k4[2]; t2 = fmaf(2.0f, k2[6], t2); t2 = fmaf(2.0f, k3[4], t2);
    float t3 = k1[9] + k4[3]; t3 = fmaf(2.0f, k2[7], t3); t3 = fmaf(2.0f, k3[5], t3);
    r.x = fmaf(sc, t0, xa[8]);
    r.y = fmaf(sc, t1, xa[9]);
    r.z = fmaf(sc, t2, xa[10]);
    r.w = fmaf(sc, t3, xa[11]);
    return r;
}

__global__ __launch_bounds__(256)
void lorenz96_rk4_persist(const float4* __restrict__ x0,
                          const float* __restrict__ dt_p,
                          float4* __restrict__ out,
                          unsigned nf4,      // batch*10 float4s (multiple of 10)
                          unsigned stride,   // total threads in grid
                          int cstep,         // stride % 10
                          int niter)         // ceil(nf4/stride), even
{
    const unsigned tid = blockIdx.x * blockDim.x + threadIdx.x;

    const float dt  = dt_p[0];
    const float hdt = 0.5f * dt;

    float4 A0, B0, C0, D0;   // slot 0
    float4 A1, B1, C1, D1;   // slot 1

    // LOADS(f, c): issue the 4 stencil loads for chunk f (column c)
#define LOADS(F, C, A, B, Cc, D)                                             \
    {                                                                        \
        const int om2 = ((C) >= 2) ? -2 : 8;                                 \
        const int om1 = ((C) >= 1) ? -1 : 9;                                 \
        const int op1 = ((C) <= 8) ?  1 : -9;                                \
        A  = x0[(F) + om2];                                                  \
        B  = x0[(F) + om1];                                                  \
        Cc = x0[(F)];                                                        \
        D  = x0[(F) + op1];                                                  \
    }

    unsigned f0 = tid;
    int      c0 = (int)(f0 % 10u);
    bool   act0 = (f0 < nf4);
    if (act0) LOADS(f0, c0, A0, B0, C0, D0)

    unsigned f1 = f0 + stride;
    int      c1 = c0 + cstep; if (c1 >= 10) c1 -= 10;

    for (int it = 0; it < niter; it += 2) {
        // prefetch slot 1, then compute/store slot 0
        const bool act1 = (f1 < nf4);
        if (act1) LOADS(f1, c1, A1, B1, C1, D1)
        if (act0) out[f0] = rk4_chunk(A0, B0, C0, D0, dt, hdt);

        f0 = f1 + stride;
        c0 = c1 + cstep; if (c0 >= 10) c0 -= 10;
        act0 = (f0 < nf4);

        // prefetch slot 0, then compute/store slot 1
        if (act0) LOADS(f0, c0, A0, B0, C0, D0)
        if (act1) out[f1] = rk4_chunk(A1, B1, C1, D1, dt, hdt);

        f1 = f0 + stride;
        c1 = c0 + cstep; if (c1 >= 10) c1 -= 10;
    }
#undef LOADS
}

extern "C" void kernel_launch(void* const* d_in, const int* in_sizes, int n_in,
                              void* d_out, int out_size, void* d_ws, size_t ws_size,
                              hipStream_t stream) {
    const float4* x0 = (const float4*)d_in[0];
    // d_in[1] = t (unused; autonomous system)
    const float* dt = (const float*)d_in[2];
    float4* out = (float4*)d_out;

    const unsigned nf4 = (unsigned)((long)in_sizes[0] / 4);  // batch*10 float4s
    const int block = 256;
    const unsigned grid = 2048;                  // 8 blocks/CU, persistent
    const unsigned stride = grid * block;        // 524288 threads
    const int cstep = (int)(stride % 10u);
    int niter = (int)((nf4 + stride - 1) / stride);
    if (niter & 1) ++niter;                      // loop body handles 2 iters
    lorenz96_rk4_persist<<<dim3(grid), dim3(block), 0, stream>>>(
        x0, dt, out, nf4, stride, cstep, niter);
}